// Round 1
// baseline (716.839 us; speedup 1.0000x reference)
//
#include <hip/hip_runtime.h>

#define NV 9
#define FIN 5
#define FHID 3
#define SPB 64           // samples per block (== block size, one sample/thread)
#define A_ELEMS (NV*NV)  // 81
#define H_ELEMS (NV*FIN) // 45

__global__ __launch_bounds__(64) void gcn_fused_kernel(
    const float* __restrict__ A, const float* __restrict__ h0,
    const float* __restrict__ W, const float* __restrict__ fc_w,
    const float* __restrict__ fc_b, float* __restrict__ out, int Btot)
{
    __shared__ float sA[SPB * A_ELEMS];  // 20.25 KB, sample-major (raw layout)
    __shared__ float sH[SPB * H_ELEMS];  // 11.25 KB

    const int tid = threadIdx.x;
    const long long base = (long long)blockIdx.x * SPB;
    const int cnt = (Btot - (int)base < SPB) ? (Btot - (int)base) : SPB;

    // ---- stage A block: contiguous, coalesced float4 ----
    {
        const float* gA = A + base * A_ELEMS;
        const int nflt = cnt * A_ELEMS;
        const int n4 = nflt >> 2;
        const float4* gA4 = (const float4*)gA;
        float4* lA4 = (float4*)sA;
        for (int i = tid; i < n4; i += SPB) lA4[i] = gA4[i];
        for (int i = (n4 << 2) + tid; i < nflt; i += SPB) sA[i] = gA[i];
    }
    // ---- stage h0 block ----
    {
        const float* gH = h0 + base * H_ELEMS;
        const int nflt = cnt * H_ELEMS;
        const int n4 = nflt >> 2;
        const float4* gH4 = (const float4*)gH;
        float4* lH4 = (float4*)sH;
        for (int i = tid; i < n4; i += SPB) lH4[i] = gH4[i];
        for (int i = (n4 << 2) + tid; i < nflt; i += SPB) sH[i] = gH[i];
    }

    // ---- tiny params (uniform -> scalar loads, L1/L2 cached) ----
    float Wr[FIN * FHID];
#pragma unroll
    for (int i = 0; i < FIN * FHID; i++) Wr[i] = W[i];
    const float fw0 = fc_w[0], fw1 = fc_w[1], fw2 = fc_w[2];
    const float fb = fc_b[0];

    __syncthreads();

    if (tid >= cnt) return;

    const float* Ai = sA + tid * A_ELEMS;  // stride 81 words (odd) -> 2-way bank alias only (free)
    const float* Hi = sH + tid * H_ELEMS;  // stride 45 words (odd)

    // deg[j] = 1 + sum_i A[i][j]  (column sums of A + I)
    float deg[NV];
#pragma unroll
    for (int j = 0; j < NV; j++) deg[j] = 1.0f;
#pragma unroll
    for (int i = 0; i < NV; i++) {
#pragma unroll
        for (int j = 0; j < NV; j++) deg[j] += Ai[i * NV + j];
    }
    float dinv[NV];
#pragma unroll
    for (int j = 0; j < NV; j++) dinv[j] = 1.0f / sqrtf(deg[j]);

    // G[u][h] = dinv[u] * (h0[u,:] . W[:,h])
    float G[NV * FHID];
#pragma unroll
    for (int u = 0; u < NV; u++) {
        float hr[FIN];
#pragma unroll
        for (int f = 0; f < FIN; f++) hr[f] = Hi[u * FIN + f];
#pragma unroll
        for (int h = 0; h < FHID; h++) {
            float acc = 0.0f;
#pragma unroll
            for (int f = 0; f < FIN; f++) acc += hr[f] * Wr[f * FHID + h];
            G[u * FHID + h] = dinv[u] * acc;
        }
    }

    // h2[h] = sum_v relu( dinv[v] * sum_u AI[v][u] * G[u][h] )
    float h2_0 = 0.0f, h2_1 = 0.0f, h2_2 = 0.0f;
#pragma unroll
    for (int v = 0; v < NV; v++) {
        float a0 = 0.0f, a1 = 0.0f, a2 = 0.0f;
#pragma unroll
        for (int u = 0; u < NV; u++) {
            float aiv = Ai[v * NV + u] + ((u == v) ? 1.0f : 0.0f);
            a0 += aiv * G[u * FHID + 0];
            a1 += aiv * G[u * FHID + 1];
            a2 += aiv * G[u * FHID + 2];
        }
        const float dv = dinv[v];
        a0 *= dv; a1 *= dv; a2 *= dv;
        h2_0 += fmaxf(a0, 0.0f);
        h2_1 += fmaxf(a1, 0.0f);
        h2_2 += fmaxf(a2, 0.0f);
    }

    out[base + tid] = h2_0 * fw0 + h2_1 * fw1 + h2_2 * fw2 + fb;
}

extern "C" void kernel_launch(void* const* d_in, const int* in_sizes, int n_in,
                              void* d_out, int out_size, void* d_ws, size_t ws_size,
                              hipStream_t stream) {
    const float* A    = (const float*)d_in[0];
    const float* h0   = (const float*)d_in[1];
    const float* W    = (const float*)d_in[2];
    const float* fc_w = (const float*)d_in[3];
    const float* fc_b = (const float*)d_in[4];
    float* out = (float*)d_out;

    const int Btot = in_sizes[0] / A_ELEMS;  // 1,000,000
    const int grid = (Btot + SPB - 1) / SPB;

    gcn_fused_kernel<<<grid, SPB, 0, stream>>>(A, h0, W, fc_w, fc_b, out, Btot);
}

// Round 3
// 527.849 us; speedup vs baseline: 1.3580x; 1.3580x over previous
//
#include <hip/hip_runtime.h>

#define NV 9
#define FIN 5
#define FHID 3
#define SPB 64           // samples per block (== block size, one sample/thread)
#define A_ELEMS (NV*NV)  // 81
#define H_ELEMS (NV*FIN) // 45

// One wave moves 16 B/lane = 1024 B per instruction, global -> LDS, async.
// LDS dest is wave-uniform base + lane*16 (per-lane ptr must be linear in lane).
__device__ __forceinline__ void load_lds16(const float* g, float* l) {
    __builtin_amdgcn_global_load_lds(
        (const __attribute__((address_space(1))) unsigned int*)g,
        (__attribute__((address_space(3))) unsigned int*)l, 16, 0, 0);
}

__global__ __launch_bounds__(64) void gcn_fused_kernel(
    const float* __restrict__ A, const float* __restrict__ h0,
    const float* __restrict__ W, const float* __restrict__ fc_w,
    const float* __restrict__ fc_b, float* __restrict__ out, int Btot)
{
    __shared__ float sA[SPB * A_ELEMS];  // 20.25 KB, sample-major (raw layout, no pad!)
    __shared__ float sH[SPB * H_ELEMS];  // 11.25 KB

    const int tid = threadIdx.x;
    const long long base = (long long)blockIdx.x * SPB;
    const int cnt = (Btot - (int)base < SPB) ? (Btot - (int)base) : SPB;

    const float* gA = A + base * A_ELEMS;   // 20736 B * blockIdx -> 16B aligned
    const float* gH = h0 + base * H_ELEMS;  // 11520 B * blockIdx -> 16B aligned

    if (cnt == SPB) {
        // ---- async global->LDS staging: issue ALL DMAs, then one wait ----
        // A: 20 full 1-KB wave transfers + 256 B tail (lanes 0..15)
#pragma unroll
        for (int j = 0; j < 20; j++)
            load_lds16(gA + j * 256 + tid * 4, sA + j * 256 + tid * 4);
        if (tid < 16)
            load_lds16(gA + 20 * 256 + tid * 4, sA + 20 * 256 + tid * 4);
        // h0: 11 full transfers + 256 B tail
#pragma unroll
        for (int j = 0; j < 11; j++)
            load_lds16(gH + j * 256 + tid * 4, sH + j * 256 + tid * 4);
        if (tid < 16)
            load_lds16(gH + 11 * 256 + tid * 4, sH + 11 * 256 + tid * 4);
    } else {
        // generic fallback (never hit at B=1e6, keeps arbitrary B correct)
        const int nfltA = cnt * A_ELEMS;
        for (int i = tid; i < nfltA; i += SPB) sA[i] = gA[i];
        const int nfltH = cnt * H_ELEMS;
        for (int i = tid; i < nfltH; i += SPB) sH[i] = gH[i];
    }

    // ---- tiny params (uniform -> scalar loads, cached) ----
    float Wr[FIN * FHID];
#pragma unroll
    for (int i = 0; i < FIN * FHID; i++) Wr[i] = W[i];
    const float fw0 = fc_w[0], fw1 = fc_w[1], fw2 = fc_w[2];
    const float fb = fc_b[0];

    // RACE FIX: compiler does not model global_load_lds's LDS write, and a
    // single-wave block lets it weaken __syncthreads — force the drain.
    asm volatile("s_waitcnt vmcnt(0)" ::: "memory");
    __syncthreads();

    if (tid >= cnt) return;

    const float* Ai = sA + tid * A_ELEMS;  // stride 81 words (odd) -> only free 2-way alias
    const float* Hi = sH + tid * H_ELEMS;  // stride 45 words (odd)

    // deg[j] = 1 + sum_i A[i][j]  (column sums of A + I)
    float deg[NV];
#pragma unroll
    for (int j = 0; j < NV; j++) deg[j] = 1.0f;
#pragma unroll
    for (int i = 0; i < NV; i++) {
#pragma unroll
        for (int j = 0; j < NV; j++) deg[j] += Ai[i * NV + j];
    }
    float dinv[NV];
#pragma unroll
    for (int j = 0; j < NV; j++) dinv[j] = 1.0f / sqrtf(deg[j]);

    // G[u][h] = dinv[u] * (h0[u,:] . W[:,h])
    float G[NV * FHID];
#pragma unroll
    for (int u = 0; u < NV; u++) {
        float hr[FIN];
#pragma unroll
        for (int f = 0; f < FIN; f++) hr[f] = Hi[u * FIN + f];
#pragma unroll
        for (int h = 0; h < FHID; h++) {
            float acc = 0.0f;
#pragma unroll
            for (int f = 0; f < FIN; f++) acc += hr[f] * Wr[f * FHID + h];
            G[u * FHID + h] = dinv[u] * acc;
        }
    }

    // h2[h] = sum_v relu( dinv[v] * sum_u AI[v][u] * G[u][h] )
    float h2_0 = 0.0f, h2_1 = 0.0f, h2_2 = 0.0f;
#pragma unroll
    for (int v = 0; v < NV; v++) {
        float a0 = 0.0f, a1 = 0.0f, a2 = 0.0f;
#pragma unroll
        for (int u = 0; u < NV; u++) {
            float aiv = Ai[v * NV + u] + ((u == v) ? 1.0f : 0.0f);
            a0 += aiv * G[u * FHID + 0];
            a1 += aiv * G[u * FHID + 1];
            a2 += aiv * G[u * FHID + 2];
        }
        const float dv = dinv[v];
        a0 *= dv; a1 *= dv; a2 *= dv;
        h2_0 += fmaxf(a0, 0.0f);
        h2_1 += fmaxf(a1, 0.0f);
        h2_2 += fmaxf(a2, 0.0f);
    }

    out[base + tid] = h2_0 * fw0 + h2_1 * fw1 + h2_2 * fw2 + fb;
}

extern "C" void kernel_launch(void* const* d_in, const int* in_sizes, int n_in,
                              void* d_out, int out_size, void* d_ws, size_t ws_size,
                              hipStream_t stream) {
    const float* A    = (const float*)d_in[0];
    const float* h0   = (const float*)d_in[1];
    const float* W    = (const float*)d_in[2];
    const float* fc_w = (const float*)d_in[3];
    const float* fc_b = (const float*)d_in[4];
    float* out = (float*)d_out;

    const int Btot = in_sizes[0] / A_ELEMS;  // 1,000,000
    const int grid = (Btot + SPB - 1) / SPB;

    gcn_fused_kernel<<<grid, SPB, 0, stream>>>(A, h0, W, fc_w, fc_b, out, Btot);
}